// Round 1
// baseline (2193.212 us; speedup 1.0000x reference)
//
#include <hip/hip_runtime.h>
#include <hip/hip_bf16.h>
#include <math.h>

#define NH   16
#define NKV  4
#define HD   128
#define DM   2048
#define KVD  512
#define LSEQ 2048
#define BATCH 2
#define MROWS (BATCH*LSEQ)      // 4096
#define NQKV  (DM + 2*KVD)      // 3072

// ---------------- RoPE tables (precomputed trig, G13) ----------------
__global__ void rope_tables_k(float* __restrict__ cosT, float* __restrict__ sinT) {
  int idx = blockIdx.x * 256 + threadIdx.x;
  if (idx >= LSEQ * 64) return;
  int l = idx >> 6, i = idx & 63;
  float inv = powf(10000.0f, -(float)i * (1.0f/64.0f));
  float f = (float)l * inv;
  cosT[idx] = cosf(f);
  sinT[idx] = sinf(f);
}

// ---------------- GEMM: C[m,n] = sum_k A[m,k] * W[n,k] (TN, fp32) ----------------
// MODE 0: plain store to O0 (row-major M x N)
// MODE 1: QKV fused — W selected per column-block, epilogue scatters to (B,H,L,hd)
template<int MODE>
__global__ __launch_bounds__(256, 3)
void gemm_tn_k(const float* __restrict__ A,
               const float* __restrict__ W0, const float* __restrict__ W1, const float* __restrict__ W2,
               float* __restrict__ O0, float* __restrict__ O1, float* __restrict__ O2,
               int N, int K)
{
  __shared__ __align__(16) float a_s[32][128];   // [k][m] transposed
  __shared__ __align__(16) float b_s[32][128];   // [k][n] transposed
  const int tid = threadIdx.x;
  const int tx = tid & 15, ty = tid >> 4;
  const int bm = blockIdx.x * 128;
  const int bn = blockIdx.y * 128;
  const int sr = tid >> 1;            // staging row (128 rows, 2 thr/row)
  const int sc0 = (tid & 1) * 16;     // staging col half

  const float* Wbase = W0;
  int nb = bn, region = 0;
  if (MODE == 1) {
    if (bn >= DM + KVD)   { Wbase = W2; nb = bn - DM - KVD; region = 2; }
    else if (bn >= DM)    { Wbase = W1; nb = bn - DM;       region = 1; }
  }

  const float* Ap = A     + (size_t)(bm + sr) * K + sc0;
  const float* Wp = Wbase + (size_t)(nb + sr) * K + sc0;

  float4 av[4], wv[4];
#pragma unroll
  for (int j = 0; j < 4; ++j) {
    av[j] = *(const float4*)(Ap + j*4);
    wv[j] = *(const float4*)(Wp + j*4);
  }

  float acc[8][8];
#pragma unroll
  for (int i = 0; i < 8; ++i)
#pragma unroll
    for (int j = 0; j < 8; ++j) acc[i][j] = 0.0f;

  const int nt = K >> 5;
  for (int t = 0; t < nt; ++t) {
    __syncthreads();
#pragma unroll
    for (int j = 0; j < 4; ++j) {   // transpose-store to LDS (2-way, free)
      a_s[sc0 + j*4 + 0][sr] = av[j].x;
      a_s[sc0 + j*4 + 1][sr] = av[j].y;
      a_s[sc0 + j*4 + 2][sr] = av[j].z;
      a_s[sc0 + j*4 + 3][sr] = av[j].w;
      b_s[sc0 + j*4 + 0][sr] = wv[j].x;
      b_s[sc0 + j*4 + 1][sr] = wv[j].y;
      b_s[sc0 + j*4 + 2][sr] = wv[j].z;
      b_s[sc0 + j*4 + 3][sr] = wv[j].w;
    }
    __syncthreads();
    if (t + 1 < nt) {               // prefetch next tile into regs (overlaps compute)
      const float* Ap2 = Ap + (t+1)*32;
      const float* Wp2 = Wp + (t+1)*32;
#pragma unroll
      for (int j = 0; j < 4; ++j) {
        av[j] = *(const float4*)(Ap2 + j*4);
        wv[j] = *(const float4*)(Wp2 + j*4);
      }
    }
#pragma unroll 8
    for (int kk = 0; kk < 32; ++kk) {
      float ar[8], br[8];
      *(float4*)&ar[0] = *(const float4*)&a_s[kk][ty*4];        // rows ty*4..+3
      *(float4*)&ar[4] = *(const float4*)&a_s[kk][64 + ty*4];   // rows 64+ty*4..+3
      *(float4*)&br[0] = *(const float4*)&b_s[kk][tx*4];
      *(float4*)&br[4] = *(const float4*)&b_s[kk][64 + tx*4];
#pragma unroll
      for (int i = 0; i < 8; ++i)
#pragma unroll
        for (int j = 0; j < 8; ++j)
          acc[i][j] = fmaf(ar[i], br[j], acc[i][j]);
    }
  }

#pragma unroll
  for (int i = 0; i < 8; ++i) {
    const int row = bm + ((i < 4) ? (ty*4 + i) : (64 + ty*4 + (i-4)));
#pragma unroll
    for (int g = 0; g < 2; ++g) {
      const int coff = g ? (64 + tx*4) : (tx*4);
      float4 v = make_float4(acc[i][g*4+0], acc[i][g*4+1], acc[i][g*4+2], acc[i][g*4+3]);
      if (MODE == 0) {
        *(float4*)(O0 + (size_t)row * N + bn + coff) = v;
      } else {
        const int col = nb + coff;        // col within selected weight matrix
        const int h = col >> 7, d = col & 127;
        const int b = row >> 11, l = row & (LSEQ-1);
        float* dst; int heads;
        if (region == 0)      { dst = O0; heads = NH;  }
        else if (region == 1) { dst = O1; heads = NKV; }
        else                  { dst = O2; heads = NKV; }
        *(float4*)(dst + (((size_t)(b*heads + h) * LSEQ + l) * HD + d)) = v;
      }
    }
  }
}

// ---------------- RoPE in-place on Q and K ----------------
__global__ void rope_k(float* __restrict__ Q, float* __restrict__ Kt,
                       const float* __restrict__ cosT, const float* __restrict__ sinT)
{
  const int gid = blockIdx.x * 256 + threadIdx.x;
  const int row = gid >> 4;            // one (b,h,l) row per 16 threads
  const int i0  = (gid & 15) * 4;      // freq index base
  const int QROWS = BATCH * NH * LSEQ;
  const int TROWS = QROWS + BATCH * NKV * LSEQ;
  if (row >= TROWS) return;
  float* base = (row < QROWS) ? (Q + (size_t)row * HD)
                              : (Kt + (size_t)(row - QROWS) * HD);
  const int l = row & (LSEQ - 1);
  float4 x1 = *(float4*)(base + i0);
  float4 x2 = *(float4*)(base + 64 + i0);
  float4 c  = *(const float4*)(cosT + l*64 + i0);
  float4 s  = *(const float4*)(sinT + l*64 + i0);
  float4 o1, o2;
  o1.x = x1.x*c.x - x2.x*s.x;  o2.x = x2.x*c.x + x1.x*s.x;
  o1.y = x1.y*c.y - x2.y*s.y;  o2.y = x2.y*c.y + x1.y*s.y;
  o1.z = x1.z*c.z - x2.z*s.z;  o2.z = x2.z*c.z + x1.z*s.z;
  o1.w = x1.w*c.w - x2.w*s.w;  o2.w = x2.w*c.w + x1.w*s.w;
  *(float4*)(base + i0)      = o1;
  *(float4*)(base + 64 + i0) = o2;
}

// ---------------- Flash attention (fp32, causal, GQA) ----------------
// grid: (qtile=32, bh=32); block 256. BQ=64 q-rows, BKEY=32 keys per tile.
__global__ __launch_bounds__(256, 2)
void attn_k(const float* __restrict__ Q, const float* __restrict__ K,
            const float* __restrict__ V, float* __restrict__ AO)
{
  __shared__ __align__(16) float q_s[HD][64];    // [d][r]  32 KB
  __shared__ __align__(16) float k_s[HD][32];    // [d][c]  16 KB
  __shared__ __align__(16) float v_s[32][132];   // [kk][d] padded, 16.5 KB
  __shared__ __align__(16) float p_s[32][68];    // [c][r]  padded, 8.5 KB
  const int tid = threadIdx.x;
  const int tx = tid & 15, ty = tid >> 4;
  const int qt = blockIdx.x;
  const int bh = blockIdx.y;
  const int b = bh >> 4, h = bh & 15;
  const int kh = h >> 2;                 // GQA: 4 q-heads per kv-head
  const int q0 = qt * 64;
  const float* Qp = Q + ((size_t)bh * LSEQ + q0) * HD;
  const float* Kp = K + ((size_t)(b*NKV + kh) * LSEQ) * HD;
  const float* Vp = V + ((size_t)(b*NKV + kh) * LSEQ) * HD;

  { // stage Q transposed (once)
    const int r = tid >> 2, d0 = (tid & 3) * 32;
#pragma unroll
    for (int j = 0; j < 8; ++j) {
      float4 vq = *(const float4*)(Qp + r*HD + d0 + j*4);
      q_s[d0 + j*4 + 0][r] = vq.x;
      q_s[d0 + j*4 + 1][r] = vq.y;
      q_s[d0 + j*4 + 2][r] = vq.z;
      q_s[d0 + j*4 + 3][r] = vq.w;
    }
  }

  float accO[4][8];                      // rows ty*4+rr; cols tx*4..+3 and 64+tx*4..+3
#pragma unroll
  for (int i = 0; i < 4; ++i)
#pragma unroll
    for (int j = 0; j < 8; ++j) accO[i][j] = 0.0f;
  float mrow[4] = {-INFINITY, -INFINITY, -INFINITY, -INFINITY};
  float lrow[4] = {0.f, 0.f, 0.f, 0.f};
  const float scale = 0.08838834764831845f;   // 1/sqrt(128)

  const int ntile = qt*2 + 2;            // keys 0 .. q0+63
  for (int t = 0; t < ntile; ++t) {
    const int k0 = t * 32;
    __syncthreads();                     // prev PV done; LDS free
    { // stage K transposed + V row-major
      const int c = tid >> 3, d0 = (tid & 7) * 16;
      const float* kp = Kp + (size_t)(k0 + c) * HD + d0;
      const float* vp = Vp + (size_t)(k0 + c) * HD + d0;
#pragma unroll
      for (int j = 0; j < 4; ++j) {
        float4 kv = *(const float4*)(kp + j*4);
        k_s[d0 + j*4 + 0][c] = kv.x;
        k_s[d0 + j*4 + 1][c] = kv.y;
        k_s[d0 + j*4 + 2][c] = kv.z;
        k_s[d0 + j*4 + 3][c] = kv.w;
        *(float4*)&v_s[c][d0 + j*4] = *(const float4*)(vp + j*4);
      }
    }
    __syncthreads();

    // S = Q K^T tile: 4 rows x 2 cols per thread
    float s[4][2];
#pragma unroll
    for (int i = 0; i < 4; ++i) { s[i][0] = 0.f; s[i][1] = 0.f; }
#pragma unroll 8
    for (int d = 0; d < HD; ++d) {
      float4 qv = *(const float4*)&q_s[d][ty*4];
      float2 kv = *(const float2*)&k_s[d][tx*2];
      s[0][0] = fmaf(qv.x, kv.x, s[0][0]);  s[0][1] = fmaf(qv.x, kv.y, s[0][1]);
      s[1][0] = fmaf(qv.y, kv.x, s[1][0]);  s[1][1] = fmaf(qv.y, kv.y, s[1][1]);
      s[2][0] = fmaf(qv.z, kv.x, s[2][0]);  s[2][1] = fmaf(qv.z, kv.y, s[2][1]);
      s[3][0] = fmaf(qv.w, kv.x, s[3][0]);  s[3][1] = fmaf(qv.w, kv.y, s[3][1]);
    }

    // scale + causal mask
#pragma unroll
    for (int rr = 0; rr < 4; ++rr) {
      const int qabs = q0 + ty*4 + rr;
#pragma unroll
      for (int cc = 0; cc < 2; ++cc) {
        const int kabs = k0 + tx*2 + cc;
        s[rr][cc] = (kabs <= qabs) ? s[rr][cc] * scale : -INFINITY;
      }
    }

    // row max across the 16 tx lanes of each row group
    float pm[4];
#pragma unroll
    for (int rr = 0; rr < 4; ++rr) pm[rr] = fmaxf(s[rr][0], s[rr][1]);
#pragma unroll
    for (int off = 1; off < 16; off <<= 1)
#pragma unroll
      for (int rr = 0; rr < 4; ++rr)
        pm[rr] = fmaxf(pm[rr], __shfl_xor(pm[rr], off, 64));

    float p[4][2], rs[4];
#pragma unroll
    for (int rr = 0; rr < 4; ++rr) {
      const float mnew = fmaxf(mrow[rr], pm[rr]);      // finite after tile 0
      const float fac  = __expf(mrow[rr] - mnew);      // exp(-inf)=0 first tile
      p[rr][0] = __expf(s[rr][0] - mnew);
      p[rr][1] = __expf(s[rr][1] - mnew);
      rs[rr] = p[rr][0] + p[rr][1];
      mrow[rr] = mnew;
      lrow[rr] *= fac;
#pragma unroll
      for (int j = 0; j < 8; ++j) accO[rr][j] *= fac;
    }
#pragma unroll
    for (int off = 1; off < 16; off <<= 1)
#pragma unroll
      for (int rr = 0; rr < 4; ++rr)
        rs[rr] += __shfl_xor(rs[rr], off, 64);
#pragma unroll
    for (int rr = 0; rr < 4; ++rr) lrow[rr] += rs[rr];

    // stage P transposed
#pragma unroll
    for (int rr = 0; rr < 4; ++rr) {
      p_s[tx*2 + 0][ty*4 + rr] = p[rr][0];
      p_s[tx*2 + 1][ty*4 + rr] = p[rr][1];
    }
    __syncthreads();

    // O += P V
#pragma unroll 4
    for (int kk = 0; kk < 32; ++kk) {
      float4 pv = *(const float4*)&p_s[kk][ty*4];
      float4 v0 = *(const float4*)&v_s[kk][tx*4];
      float4 v1 = *(const float4*)&v_s[kk][64 + tx*4];
      float pr[4] = {pv.x, pv.y, pv.z, pv.w};
      float vr[8] = {v0.x,v0.y,v0.z,v0.w,v1.x,v1.y,v1.z,v1.w};
#pragma unroll
      for (int i = 0; i < 4; ++i)
#pragma unroll
        for (int j = 0; j < 8; ++j)
          accO[i][j] = fmaf(pr[i], vr[j], accO[i][j]);
    }
  }

  // normalize + store to (B, L, D) layout for the output GEMM
  float* aob = AO + (size_t)(b * LSEQ + q0) * DM + h * HD;
#pragma unroll
  for (int rr = 0; rr < 4; ++rr) {
    const float inv = 1.0f / lrow[rr];
    const int r = ty*4 + rr;
    float4 o0 = make_float4(accO[rr][0]*inv, accO[rr][1]*inv, accO[rr][2]*inv, accO[rr][3]*inv);
    float4 o1 = make_float4(accO[rr][4]*inv, accO[rr][5]*inv, accO[rr][6]*inv, accO[rr][7]*inv);
    *(float4*)(aob + (size_t)r * DM + tx*4)      = o0;
    *(float4*)(aob + (size_t)r * DM + 64 + tx*4) = o1;
  }
}

extern "C" void kernel_launch(void* const* d_in, const int* in_sizes, int n_in,
                              void* d_out, int out_size, void* d_ws, size_t ws_size,
                              hipStream_t stream)
{
  const float* x  = (const float*)d_in[0];
  const float* Wq = (const float*)d_in[1];
  const float* Wk = (const float*)d_in[2];
  const float* Wv = (const float*)d_in[3];
  const float* Wo = (const float*)d_in[4];
  float* out = (float*)d_out;

  // workspace carve: 81.2 MB total
  float* q_ws  = (float*)d_ws;                       // 4096*2048
  float* k_ws  = q_ws  + (size_t)MROWS * DM;         // 4096*512
  float* v_ws  = k_ws  + (size_t)MROWS * KVD;        // 4096*512
  float* ao_ws = v_ws  + (size_t)MROWS * KVD;        // 4096*2048
  float* cosT  = ao_ws + (size_t)MROWS * DM;         // 2048*64
  float* sinT  = cosT  + (size_t)LSEQ * 64;          // 2048*64

  rope_tables_k<<<(LSEQ*64 + 255)/256, 256, 0, stream>>>(cosT, sinT);

  dim3 g1(MROWS/128, NQKV/128);   // 32 x 24
  gemm_tn_k<1><<<g1, 256, 0, stream>>>(x, Wq, Wk, Wv, q_ws, k_ws, v_ws, NQKV, DM);

  rope_k<<<(BATCH*(NH+NKV)*LSEQ*16)/256, 256, 0, stream>>>(q_ws, k_ws, cosT, sinT);

  dim3 g2(LSEQ/64, BATCH*NH);     // 32 x 32
  attn_k<<<g2, 256, 0, stream>>>(q_ws, k_ws, v_ws, ao_ws);

  dim3 g3(MROWS/128, DM/128);     // 32 x 16
  gemm_tn_k<0><<<g3, 256, 0, stream>>>(ao_ws, Wo, nullptr, nullptr, out, nullptr, nullptr, DM, DM);
}

// Round 7
// 680.403 us; speedup vs baseline: 3.2234x; 3.2234x over previous
//
#include <hip/hip_runtime.h>
#include <hip/hip_bf16.h>
#include <math.h>

#define NH 16
#define NKV 4
#define HD 128
#define DM 2048
#define KVD 512
#define LSEQ 2048
#define BATCH 2
#define MROWS (BATCH*LSEQ)
#define NQKV (DM+2*KVD)

typedef __bf16 bf16x8 __attribute__((ext_vector_type(8)));
typedef float f32x4 __attribute__((ext_vector_type(4)));

#define MFMA16(a,b,c) __builtin_amdgcn_mfma_f32_16x16x32_bf16((a),(b),(c),0,0,0)

__device__ __forceinline__ unsigned short f2bf(float f) {
  unsigned int u = __float_as_uint(f);
  return (unsigned short)((u + 0x7FFFu + ((u >> 16) & 1u)) >> 16);
}
__device__ __forceinline__ float bf2f(unsigned short b) {
  return __uint_as_float(((unsigned int)b) << 16);
}
__device__ __forceinline__ void unpack8(uint4 v, float* f) {
  f[0]=bf2f(v.x&0xffff); f[1]=bf2f(v.x>>16); f[2]=bf2f(v.y&0xffff); f[3]=bf2f(v.y>>16);
  f[4]=bf2f(v.z&0xffff); f[5]=bf2f(v.z>>16); f[6]=bf2f(v.w&0xffff); f[7]=bf2f(v.w>>16);
}
__device__ __forceinline__ uint4 pack8(const float* f) {
  uint4 v;
  v.x = (unsigned)f2bf(f[0]) | ((unsigned)f2bf(f[1])<<16);
  v.y = (unsigned)f2bf(f[2]) | ((unsigned)f2bf(f[3])<<16);
  v.z = (unsigned)f2bf(f[4]) | ((unsigned)f2bf(f[5])<<16);
  v.w = (unsigned)f2bf(f[6]) | ((unsigned)f2bf(f[7])<<16);
  return v;
}

// ---------- fp32 -> bf16 conversion ----------
__global__ void conv_k(const float* __restrict__ src, unsigned short* __restrict__ dst, int n4) {
  int i = blockIdx.x*256 + threadIdx.x;
  int stride = gridDim.x*256;
  for (; i < n4; i += stride) {
    float4 v = ((const float4*)src)[i];
    ushort4 o;
    o.x = f2bf(v.x); o.y = f2bf(v.y); o.z = f2bf(v.z); o.w = f2bf(v.w);
    ((ushort4*)dst)[i] = o;
  }
}

// ---------- RoPE tables ----------
__global__ void rope_tab_k(float* __restrict__ cosT, float* __restrict__ sinT) {
  int idx = blockIdx.x*256 + threadIdx.x;
  if (idx >= LSEQ*64) return;
  int l = idx >> 6, i = idx & 63;
  float inv = powf(10000.0f, -(float)i * (1.0f/64.0f));
  float f = (float)l * inv;
  cosT[idx] = cosf(f);
  sinT[idx] = sinf(f);
}

// ---------- RoPE applied in-place on bf16 Q (with softmax scale folded) and K ----------
__global__ void rope_apply_k(unsigned short* __restrict__ Q, unsigned short* __restrict__ Kt,
                             const float* __restrict__ cosT, const float* __restrict__ sinT) {
  const int QROWS = BATCH*NH*LSEQ;
  const int TROWS = QROWS + BATCH*NKV*LSEQ;
  int t = blockIdx.x*256 + threadIdx.x;
  int row = t >> 3, p = t & 7;          // 8 threads per row; each owns hd0 and hd0+64 (race-free)
  if (row >= TROWS) return;
  unsigned short* base; float mul;
  if (row < QROWS) { base = Q + (size_t)row*HD; mul = 0.08838834764831845f; }
  else             { base = Kt + (size_t)(row-QROWS)*HD; mul = 1.0f; }
  const int l = row & (LSEQ-1);
  const int hd0 = p*8;
  float x1[8], x2[8], o1[8], o2[8];
  unpack8(*(const uint4*)(base + hd0), x1);
  unpack8(*(const uint4*)(base + 64 + hd0), x2);
  const float* cp = cosT + l*64 + hd0;
  const float* sp = sinT + l*64 + hd0;
#pragma unroll
  for (int j = 0; j < 8; ++j) {
    float c = cp[j], s = sp[j];
    o1[j] = (x1[j]*c - x2[j]*s) * mul;
    o2[j] = (x2[j]*c + x1[j]*s) * mul;
  }
  *(uint4*)(base + hd0)      = pack8(o1);
  *(uint4*)(base + 64 + hd0) = pack8(o2);
}

// ---------- bf16 MFMA GEMM: C[m,n] = sum_k A[m,k]*W[n,k] ----------
// MODE 0: fused QKV, bf16 scatter epilogue to (B,H,L,hd) arrays
// MODE 1: fp32 row-major store
template<int MODE>
__global__ __launch_bounds__(256, 3)
void gemm_k(const unsigned short* __restrict__ A,
            const unsigned short* __restrict__ Wq_, const unsigned short* __restrict__ Wk_,
            const unsigned short* __restrict__ Wv_,
            unsigned short* __restrict__ Oq, unsigned short* __restrict__ Ok,
            unsigned short* __restrict__ Ov, float* __restrict__ Of)
{
  __shared__ __align__(16) unsigned short a_s[128*40];   // padded stride 40 (2-way banks)
  __shared__ __align__(16) unsigned short b_s[128*40];
  const int tid = threadIdx.x;
  const int lane = tid & 63, w = tid >> 6;
  const int wm = w >> 1, wn = w & 1;
  const int lx = lane & 15, lg = lane >> 4;
  const int bm = blockIdx.x * 128;
  const int bn = blockIdx.y * 128;
  const int K = DM;

  const unsigned short* Wb; int start, heads;
  if (MODE == 0) {
    if (bn >= DM+KVD)  { Wb = Wv_; start = DM+KVD; heads = NKV; }
    else if (bn >= DM) { Wb = Wk_; start = DM;     heads = NKV; }
    else               { Wb = Wq_; start = 0;      heads = NH;  }
  } else { Wb = Wq_; start = 0; heads = 0; }
  const int bnl = bn - start;

  const int sr = tid >> 2, sk = (tid & 3) * 8;   // staging: rows sr & 64+sr, 8-elem chunk sk
  const unsigned short* Ap = A  + (size_t)(bm + sr) * K + sk;
  const unsigned short* Bp = Wb + (size_t)(bnl + sr) * K + sk;

  uint4 av[2], bv[2];
  av[0] = *(const uint4*)(Ap);  av[1] = *(const uint4*)(Ap + (size_t)64*K);
  bv[0] = *(const uint4*)(Bp);  bv[1] = *(const uint4*)(Bp + (size_t)64*K);

  f32x4 acc[4][4];
#pragma unroll
  for (int i = 0; i < 4; ++i)
#pragma unroll
    for (int j = 0; j < 4; ++j) acc[i][j] = (f32x4){0.f,0.f,0.f,0.f};

  const int nt = K / 32;
  for (int t = 0; t < nt; ++t) {
    if (t) __syncthreads();
    *(uint4*)&a_s[sr*40 + sk]      = av[0];
    *(uint4*)&a_s[(64+sr)*40 + sk] = av[1];
    *(uint4*)&b_s[sr*40 + sk]      = bv[0];
    *(uint4*)&b_s[(64+sr)*40 + sk] = bv[1];
    __syncthreads();
    if (t+1 < nt) {   // prefetch next K-step into regs; overlaps MFMA below
      const unsigned short* Ap2 = Ap + (t+1)*32;
      const unsigned short* Bp2 = Bp + (t+1)*32;
      av[0] = *(const uint4*)(Ap2); av[1] = *(const uint4*)(Ap2 + (size_t)64*K);
      bv[0] = *(const uint4*)(Bp2); bv[1] = *(const uint4*)(Bp2 + (size_t)64*K);
    }
    bf16x8 af[4], bfr[4];
#pragma unroll
    for (int mi = 0; mi < 4; ++mi)
      af[mi] = *(const bf16x8*)&a_s[(wm*64 + mi*16 + lx)*40 + lg*8];
#pragma unroll
    for (int ni = 0; ni < 4; ++ni)
      bfr[ni] = *(const bf16x8*)&b_s[(wn*64 + ni*16 + lx)*40 + lg*8];
#pragma unroll
    for (int mi = 0; mi < 4; ++mi)
#pragma unroll
      for (int ni = 0; ni < 4; ++ni)
        acc[mi][ni] = MFMA16(af[mi], bfr[ni], acc[mi][ni]);
  }

  if (MODE == 1) {
#pragma unroll
    for (int mi = 0; mi < 4; ++mi)
#pragma unroll
      for (int reg = 0; reg < 4; ++reg) {
        const int row = bm + wm*64 + mi*16 + lg*4 + reg;
        float* orow = Of + (size_t)row*DM + bn + wn*64 + lx;
#pragma unroll
        for (int ni = 0; ni < 4; ++ni) orow[ni*16] = acc[mi][ni][reg];
      }
  } else {
    unsigned short* dst = (start == 0) ? Oq : ((start == DM) ? Ok : Ov);
#pragma unroll
    for (int mi = 0; mi < 4; ++mi)
#pragma unroll
      for (int reg = 0; reg < 4; ++reg) {
        const int row = bm + wm*64 + mi*16 + lg*4 + reg;
        const int b = row >> 11, lseq = row & (LSEQ-1);
#pragma unroll
        for (int ni = 0; ni < 4; ++ni) {
          const int c = bnl + wn*64 + ni*16 + lx;
          const int h = c >> 7, hd = c & 127;
          dst[(((size_t)(b*heads + h))*LSEQ + lseq)*HD + hd] = f2bf(acc[mi][ni][reg]);
        }
      }
  }
}

// ---------- bf16 MFMA flash attention (causal, GQA) ----------
// grid (16 qtiles, 32 bh), 256 thr = 4 waves; 128 q-rows/block (32/wave), KV tile 64.
__global__ __launch_bounds__(256, 2)
void attn_k(const unsigned short* __restrict__ Q, const unsigned short* __restrict__ K,
            const unsigned short* __restrict__ V, unsigned short* __restrict__ AO)
{
  __shared__ __align__(16) unsigned short k_s[64*136];   // [key][hd] padded
  __shared__ __align__(16) unsigned short v_t[128*72];   // [hd][key] padded (transposed)
  __shared__ __align__(16) unsigned short p_s[4*32*72];  // per-wave [32 q][64 key] padded
  const int tid = threadIdx.x, lane = tid & 63, w = tid >> 6;
  const int lx = lane & 15, lg = lane >> 4;
  const int bh = blockIdx.y;
  const int b = bh >> 4, h = bh & 15, kh = h >> 2;
  int qt = blockIdx.x; if (bh & 1) qt = 15 - qt;   // mix heavy/light tiles across dispatch
  const int q0 = qt*128;
  const int qw = q0 + w*32;
  const unsigned short* Qp = Q + ((size_t)(b*NH + h)*LSEQ)*HD;
  const unsigned short* Kp = K + ((size_t)(b*NKV + kh)*LSEQ)*HD;
  const unsigned short* Vp = V + ((size_t)(b*NKV + kh)*LSEQ)*HD;

  bf16x8 qf[2][4];                                 // Q frags (pre-roped, pre-scaled)
#pragma unroll
  for (int mi = 0; mi < 2; ++mi)
#pragma unroll
    for (int kf = 0; kf < 4; ++kf)
      qf[mi][kf] = *(const bf16x8*)(Qp + (size_t)(qw + mi*16 + lx)*HD + kf*32 + lg*8);

  f32x4 accO[2][8];
#pragma unroll
  for (int i = 0; i < 2; ++i)
#pragma unroll
    for (int j = 0; j < 8; ++j) accO[i][j] = (f32x4){0.f,0.f,0.f,0.f};
  float mst[2][4], lst[2][4];
#pragma unroll
  for (int i = 0; i < 2; ++i)
#pragma unroll
    for (int j = 0; j < 4; ++j) { mst[i][j] = -1e30f; lst[i][j] = 0.f; }

  const int nt = qt*2 + 2;
  for (int t = 0; t < nt; ++t) {
    const int k0 = t*64;
    if (t) __syncthreads();
    // stage K row-major (coalesced)
#pragma unroll
    for (int c = 0; c < 4; ++c) {
      int g = c*256 + tid, key = g >> 4, ch = g & 15;
      uint4 kv = *(const uint4*)(Kp + (size_t)(k0 + key)*HD + ch*8);
      *(uint4*)&k_s[key*136 + ch*8] = kv;
    }
    // stage V transposed
#pragma unroll
    for (int c = 0; c < 4; ++c) {
      int g = c*256 + tid, key = g & 63, ch = (g >> 6) & 15;
      uint4 vv = *(const uint4*)(Vp + (size_t)(k0 + key)*HD + ch*8);
      unsigned short u[8];
      u[0]=vv.x&0xffff; u[1]=vv.x>>16; u[2]=vv.y&0xffff; u[3]=vv.y>>16;
      u[4]=vv.z&0xffff; u[5]=vv.z>>16; u[6]=vv.w&0xffff; u[7]=vv.w>>16;
#pragma unroll
      for (int j = 0; j < 8; ++j) v_t[(ch*8 + j)*72 + key] = u[j];
    }
    __syncthreads();

    // S = Q K^T  (per wave: 32 q x 64 key)
    f32x4 sA[2][4];
#pragma unroll
    for (int i = 0; i < 2; ++i)
#pragma unroll
      for (int j = 0; j < 4; ++j) sA[i][j] = (f32x4){0.f,0.f,0.f,0.f};
#pragma unroll
    for (int kf = 0; kf < 4; ++kf) {
      bf16x8 kfr[4];
#pragma unroll
      for (int ni = 0; ni < 4; ++ni)
        kfr[ni] = *(const bf16x8*)&k_s[(ni*16 + lx)*136 + kf*32 + lg*8];
#pragma unroll
      for (int mi = 0; mi < 2; ++mi)
#pragma unroll
        for (int ni = 0; ni < 4; ++ni)
          sA[mi][ni] = MFMA16(qf[mi][kf], kfr[ni], sA[mi][ni]);
    }

    // mask + online softmax + P -> LDS (bf16)
#pragma unroll
    for (int mi = 0; mi < 2; ++mi)
#pragma unroll
      for (int reg = 0; reg < 4; ++reg) {
        const int qabs = qw + mi*16 + lg*4 + reg;
        float sv0 = (k0 +  0 + lx <= qabs) ? sA[mi][0][reg] : -1e30f;
        float sv1 = (k0 + 16 + lx <= qabs) ? sA[mi][1][reg] : -1e30f;
        float sv2 = (k0 + 32 + lx <= qabs) ? sA[mi][2][reg] : -1e30f;
        float sv3 = (k0 + 48 + lx <= qabs) ? sA[mi][3][reg] : -1e30f;
        float pm = fmaxf(fmaxf(sv0, sv1), fmaxf(sv2, sv3));
        pm = fmaxf(pm, __shfl_xor(pm, 1));
        pm = fmaxf(pm, __shfl_xor(pm, 2));
        pm = fmaxf(pm, __shfl_xor(pm, 4));
        pm = fmaxf(pm, __shfl_xor(pm, 8));
        const float mo = mst[mi][reg];
        const float mn = fmaxf(mo, pm);
        const float fac = __expf(mo - mn);
        float p0 = __expf(sv0 - mn), p1 = __expf(sv1 - mn);
        float p2 = __expf(sv2 - mn), p3 = __expf(sv3 - mn);
        float rs = (p0 + p1) + (p2 + p3);
        rs += __shfl_xor(rs, 1); rs += __shfl_xor(rs, 2);
        rs += __shfl_xor(rs, 4); rs += __shfl_xor(rs, 8);
        mst[mi][reg] = mn;
        lst[mi][reg] = lst[mi][reg]*fac + rs;
#pragma unroll
        for (int nh = 0; nh < 8; ++nh) accO[mi][nh][reg] *= fac;
        unsigned short* pr = &p_s[w*32*72 + (mi*16 + lg*4 + reg)*72 + lx];
        pr[0]  = f2bf(p0);
        pr[16] = f2bf(p1);
        pr[32] = f2bf(p2);
        pr[48] = f2bf(p3);
      }

    // O += P V   (contraction over keys; V^T gives key-contiguous B frags)
#pragma unroll
    for (int ks = 0; ks < 2; ++ks) {
      bf16x8 pa[2];
#pragma unroll
      for (int mi = 0; mi < 2; ++mi)
        pa[mi] = *(const bf16x8*)&p_s[w*32*72 + (mi*16 + lx)*72 + ks*32 + lg*8];
#pragma unroll
      for (int nh = 0; nh < 8; ++nh) {
        bf16x8 vb = *(const bf16x8*)&v_t[(nh*16 + lx)*72 + ks*32 + lg*8];
#pragma unroll
        for (int mi = 0; mi < 2; ++mi)
          accO[mi][nh] = MFMA16(pa[mi], vb, accO[mi][nh]);
      }
    }
  }

  // normalize + store bf16 to (B,L,D) for the output GEMM
  unsigned short* aob = AO + ((size_t)b*LSEQ)*DM + (size_t)h*HD;
#pragma unroll
  for (int mi = 0; mi < 2; ++mi)
#pragma unroll
    for (int reg = 0; reg < 4; ++reg) {
      const float inv = 1.0f / lst[mi][reg];
      const int q = qw + mi*16 + lg*4 + reg;
      unsigned short* orow = aob + (size_t)q*DM;
#pragma unroll
      for (int nh = 0; nh < 8; ++nh)
        orow[nh*16 + lx] = f2bf(accO[mi][nh][reg] * inv);
    }
}

extern "C" void kernel_launch(void* const* d_in, const int* in_sizes, int n_in,
                              void* d_out, int out_size, void* d_ws, size_t ws_size,
                              hipStream_t stream)
{
  const float* x  = (const float*)d_in[0];
  const float* Wq = (const float*)d_in[1];
  const float* Wk = (const float*)d_in[2];
  const float* Wv = (const float*)d_in[3];
  const float* Wo = (const float*)d_in[4];
  float* out = (float*)d_out;

  // workspace carve (~81 MB)
  float* cosT = (float*)d_ws;                         // 2048*64
  float* sinT = cosT + LSEQ*64;
  unsigned short* xb  = (unsigned short*)(sinT + LSEQ*64);
  unsigned short* wqb = xb  + (size_t)MROWS*DM;       // 8.39M
  unsigned short* wkb = wqb + (size_t)DM*DM;          // 4.19M
  unsigned short* wvb = wkb + (size_t)KVD*DM;         // 1.05M
  unsigned short* wob = wvb + (size_t)KVD*DM;         // 1.05M
  unsigned short* qb  = wob + (size_t)DM*DM;          // 4.19M
  unsigned short* kb  = qb  + (size_t)BATCH*NH*LSEQ*HD;   // 8.39M
  unsigned short* vb  = kb  + (size_t)BATCH*NKV*LSEQ*HD;  // 2.10M
  unsigned short* aob = vb  + (size_t)BATCH*NKV*LSEQ*HD;  // 2.10M
                                                       // aob: 8.39M

  conv_k<<<2048, 256, 0, stream>>>(x,  xb,  MROWS*DM/4);
  conv_k<<<2048, 256, 0, stream>>>(Wq, wqb, DM*DM/4);
  conv_k<<<1024, 256, 0, stream>>>(Wk, wkb, KVD*DM/4);
  conv_k<<<1024, 256, 0, stream>>>(Wv, wvb, KVD*DM/4);
  conv_k<<<2048, 256, 0, stream>>>(Wo, wob, DM*DM/4);
  rope_tab_k<<<(LSEQ*64 + 255)/256, 256, 0, stream>>>(cosT, sinT);

  dim3 g1(MROWS/128, NQKV/128);   // 32 x 24
  gemm_k<0><<<g1, 256, 0, stream>>>(xb, wqb, wkb, wvb, qb, kb, vb, nullptr);

  rope_apply_k<<<(BATCH*(NH+NKV)*LSEQ*8)/256, 256, 0, stream>>>(qb, kb, cosT, sinT);

  dim3 g2(LSEQ/128, BATCH*NH);    // 16 x 32
  attn_k<<<g2, 256, 0, stream>>>(qb, kb, vb, aob);

  dim3 g3(MROWS/128, DM/128);     // 32 x 16
  gemm_k<1><<<g3, 256, 0, stream>>>(aob, wob, nullptr, nullptr, nullptr, nullptr, nullptr, out);
}

// Round 10
// 420.545 us; speedup vs baseline: 5.2152x; 1.6179x over previous
//
#include <hip/hip_runtime.h>
#include <hip/hip_bf16.h>
#include <math.h>

#define NH 16
#define NKV 4
#define HD 128
#define DM 2048
#define KVD 512
#define LSEQ 2048
#define BATCH 2
#define MROWS (BATCH*LSEQ)
#define NQKV (DM+2*KVD)

typedef __bf16 bf16x8 __attribute__((ext_vector_type(8)));
typedef float f32x4 __attribute__((ext_vector_type(4)));

#define MFMA16(a,b,c) __builtin_amdgcn_mfma_f32_16x16x32_bf16((a),(b),(c),0,0,0)

__device__ __forceinline__ unsigned short f2bf(float f) {
  unsigned int u = __float_as_uint(f);
  return (unsigned short)((u + 0x7FFFu + ((u >> 16) & 1u)) >> 16);
}
__device__ __forceinline__ float bf2f(unsigned short b) {
  return __uint_as_float(((unsigned int)b) << 16);
}
__device__ __forceinline__ void unpack8(uint4 v, float* f) {
  f[0]=bf2f(v.x&0xffff); f[1]=bf2f(v.x>>16); f[2]=bf2f(v.y&0xffff); f[3]=bf2f(v.y>>16);
  f[4]=bf2f(v.z&0xffff); f[5]=bf2f(v.z>>16); f[6]=bf2f(v.w&0xffff); f[7]=bf2f(v.w>>16);
}
__device__ __forceinline__ uint4 pack8(const float* f) {
  uint4 v;
  v.x = (unsigned)f2bf(f[0]) | ((unsigned)f2bf(f[1])<<16);
  v.y = (unsigned)f2bf(f[2]) | ((unsigned)f2bf(f[3])<<16);
  v.z = (unsigned)f2bf(f[4]) | ((unsigned)f2bf(f[5])<<16);
  v.w = (unsigned)f2bf(f[6]) | ((unsigned)f2bf(f[7])<<16);
  return v;
}

// async global->LDS, 16B per lane; LDS dest must be wave-uniform base + lane*16
__device__ __forceinline__ void gload_lds16(const unsigned short* g, unsigned short* l) {
  __builtin_amdgcn_global_load_lds(
      (__attribute__((address_space(1))) void*)(void*)const_cast<unsigned short*>(g),
      (__attribute__((address_space(3))) void*)(void*)l, 16, 0, 0);
}

// ---------- fp32 -> bf16 conversion ----------
__global__ void conv_k(const float* __restrict__ src, unsigned short* __restrict__ dst, int n4) {
  int i = blockIdx.x*256 + threadIdx.x;
  int stride = gridDim.x*256;
  for (; i < n4; i += stride) {
    float4 v = ((const float4*)src)[i];
    ushort4 o;
    o.x = f2bf(v.x); o.y = f2bf(v.y); o.z = f2bf(v.z); o.w = f2bf(v.w);
    ((ushort4*)dst)[i] = o;
  }
}

// ---------- RoPE tables ----------
__global__ void rope_tab_k(float* __restrict__ cosT, float* __restrict__ sinT) {
  int idx = blockIdx.x*256 + threadIdx.x;
  if (idx >= LSEQ*64) return;
  int l = idx >> 6, i = idx & 63;
  float inv = powf(10000.0f, -(float)i * (1.0f/64.0f));
  float f = (float)l * inv;
  cosT[idx] = cosf(f);
  sinT[idx] = sinf(f);
}

// ---------- RoPE applied in-place on bf16 Q (with softmax scale folded) and K ----------
__global__ void rope_apply_k(unsigned short* __restrict__ Q, unsigned short* __restrict__ Kt,
                             const float* __restrict__ cosT, const float* __restrict__ sinT) {
  const int QROWS = BATCH*NH*LSEQ;
  const int TROWS = QROWS + BATCH*NKV*LSEQ;
  int t = blockIdx.x*256 + threadIdx.x;
  int row = t >> 3, p = t & 7;          // 8 threads per row; each owns hd0 and hd0+64 (race-free)
  if (row >= TROWS) return;
  unsigned short* base; float mul;
  if (row < QROWS) { base = Q + (size_t)row*HD; mul = 0.08838834764831845f; }
  else             { base = Kt + (size_t)(row-QROWS)*HD; mul = 1.0f; }
  const int l = row & (LSEQ-1);
  const int hd0 = p*8;
  float x1[8], x2[8], o1[8], o2[8];
  unpack8(*(const uint4*)(base + hd0), x1);
  unpack8(*(const uint4*)(base + 64 + hd0), x2);
  const float* cp = cosT + l*64 + hd0;
  const float* sp = sinT + l*64 + hd0;
#pragma unroll
  for (int j = 0; j < 8; ++j) {
    float c = cp[j], s = sp[j];
    o1[j] = (x1[j]*c - x2[j]*s) * mul;
    o2[j] = (x2[j]*c + x1[j]*s) * mul;
  }
  *(uint4*)(base + hd0)      = pack8(o1);
  *(uint4*)(base + 64 + hd0) = pack8(o2);
}

// ---------- bf16 MFMA GEMM (m97 structure): C[m,n] = sum_k A[m,k]*W[n,k] ----------
// 128x128 tile, BK=32, 4 waves, global_load_lds width-16 into LINEAR LDS,
// 2 barriers per K-step. MODE 0: fused QKV scatter epilogue; MODE 1: fp32 store.
template<int MODE>
__global__ __launch_bounds__(256, 3)
void gemm_k(const unsigned short* __restrict__ A,
            const unsigned short* __restrict__ Wq_, const unsigned short* __restrict__ Wk_,
            const unsigned short* __restrict__ Wv_,
            unsigned short* __restrict__ Oq, unsigned short* __restrict__ Ok,
            unsigned short* __restrict__ Ov, float* __restrict__ Of)
{
  __shared__ __align__(16) unsigned short a_s[128*32];   // linear (global_load_lds needs it)
  __shared__ __align__(16) unsigned short b_s[128*32];
  const int tid = threadIdx.x;
  const int lane = tid & 63, w = tid >> 6;
  const int wm = w >> 1, wn = w & 1;
  const int lx = lane & 15, lg = lane >> 4;
  const int bm = blockIdx.x * 128;
  const int bn = blockIdx.y * 128;
  const int K = DM;

  const unsigned short* Wb; int start, heads;
  if (MODE == 0) {
    if (bn >= DM+KVD)  { Wb = Wv_; start = DM+KVD; heads = NKV; }
    else if (bn >= DM) { Wb = Wk_; start = DM;     heads = NKV; }
    else               { Wb = Wq_; start = 0;      heads = NH;  }
  } else { Wb = Wq_; start = 0; heads = 0; }
  const int bnl = bn - start;

  // staging: wave w instr i covers LDS rows (i*64 + w*16 + lane/4), cols (lane&3)*8.
  // LDS elem offset = i*2048 + w*512 + lane*8  -> byte = base + lane*16 (lane-linear). 
  const int sr0 = w*16 + (lane >> 2);
  const int sc  = (lane & 3) * 8;
  const unsigned short* Ag0 = A  + (size_t)(bm + sr0) * K + sc;
  const unsigned short* Ag1 = A  + (size_t)(bm + 64 + sr0) * K + sc;
  const unsigned short* Bg0 = Wb + (size_t)(bnl + sr0) * K + sc;
  const unsigned short* Bg1 = Wb + (size_t)(bnl + 64 + sr0) * K + sc;
  unsigned short* Al0 = &a_s[sr0*32 + sc];
  unsigned short* Al1 = &a_s[(64 + sr0)*32 + sc];
  unsigned short* Bl0 = &b_s[sr0*32 + sc];
  unsigned short* Bl1 = &b_s[(64 + sr0)*32 + sc];

  f32x4 acc[4][4];
#pragma unroll
  for (int i = 0; i < 4; ++i)
#pragma unroll
    for (int j = 0; j < 4; ++j) acc[i][j] = (f32x4){0.f,0.f,0.f,0.f};

  const int nt = K / 32;
  for (int t = 0; t < nt; ++t) {
    const int k0 = t * 32;
    if (t) __syncthreads();            // readers of tile t-1 done before overwrite
    gload_lds16(Ag0 + k0, Al0);
    gload_lds16(Ag1 + k0, Al1);
    gload_lds16(Bg0 + k0, Bl0);
    gload_lds16(Bg1 + k0, Bl1);
    __syncthreads();                   // compiler drains vmcnt(0) before s_barrier

    bf16x8 af[4], bfr[4];
#pragma unroll
    for (int mi = 0; mi < 4; ++mi)
      af[mi] = *(const bf16x8*)&a_s[(wm*64 + mi*16 + lx)*32 + lg*8];
#pragma unroll
    for (int ni = 0; ni < 4; ++ni)
      bfr[ni] = *(const bf16x8*)&b_s[(wn*64 + ni*16 + lx)*32 + lg*8];
#pragma unroll
    for (int mi = 0; mi < 4; ++mi)
#pragma unroll
      for (int ni = 0; ni < 4; ++ni)
        acc[mi][ni] = MFMA16(af[mi], bfr[ni], acc[mi][ni]);
  }

  if (MODE == 1) {
#pragma unroll
    for (int mi = 0; mi < 4; ++mi)
#pragma unroll
      for (int reg = 0; reg < 4; ++reg) {
        const int row = bm + wm*64 + mi*16 + lg*4 + reg;
        float* orow = Of + (size_t)row*DM + bn + wn*64 + lx;
#pragma unroll
        for (int ni = 0; ni < 4; ++ni) orow[ni*16] = acc[mi][ni][reg];
      }
  } else {
    unsigned short* dst = (start == 0) ? Oq : ((start == DM) ? Ok : Ov);
#pragma unroll
    for (int mi = 0; mi < 4; ++mi)
#pragma unroll
      for (int reg = 0; reg < 4; ++reg) {
        const int row = bm + wm*64 + mi*16 + lg*4 + reg;
        const int b = row >> 11, lseq = row & (LSEQ-1);
#pragma unroll
        for (int ni = 0; ni < 4; ++ni) {
          const int c = bnl + wn*64 + ni*16 + lx;
          const int h = c >> 7, hd = c & 127;
          dst[(((size_t)(b*heads + h))*LSEQ + lseq)*HD + hd] = f2bf(acc[mi][ni][reg]);
        }
      }
  }
}

// ---------- bf16 MFMA flash attention (causal, GQA) ----------
// grid (16 qtiles, 32 bh), 256 thr = 4 waves; 128 q-rows/block (32/wave), KV tile 64.
__global__ __launch_bounds__(256, 2)
void attn_k(const unsigned short* __restrict__ Q, const unsigned short* __restrict__ K,
            const unsigned short* __restrict__ V, unsigned short* __restrict__ AO)
{
  __shared__ __align__(16) unsigned short k_s[64*136];   // [key][hd] padded
  __shared__ __align__(16) unsigned short v_t[128*72];   // [hd][key] padded (transposed)
  __shared__ __align__(16) unsigned short p_s[4*32*72];  // per-wave [32 q][64 key] padded
  const int tid = threadIdx.x, lane = tid & 63, w = tid >> 6;
  const int lx = lane & 15, lg = lane >> 4;
  const int bh = blockIdx.y;
  const int b = bh >> 4, h = bh & 15, kh = h >> 2;
  int qt = blockIdx.x; if (bh & 1) qt = 15 - qt;   // mix heavy/light tiles across dispatch
  const int q0 = qt*128;
  const int qw = q0 + w*32;
  const unsigned short* Qp = Q + ((size_t)(b*NH + h)*LSEQ)*HD;
  const unsigned short* Kp = K + ((size_t)(b*NKV + kh)*LSEQ)*HD;
  const unsigned short* Vp = V + ((size_t)(b*NKV + kh)*LSEQ)*HD;

  bf16x8 qf[2][4];                                 // Q frags (pre-roped, pre-scaled)
#pragma unroll
  for (int mi = 0; mi < 2; ++mi)
#pragma unroll
    for (int kf = 0; kf < 4; ++kf)
      qf[mi][kf] = *(const bf16x8*)(Qp + (size_t)(qw + mi*16 + lx)*HD + kf*32 + lg*8);

  f32x4 accO[2][8];
#pragma unroll
  for (int i = 0; i < 2; ++i)
#pragma unroll
    for (int j = 0; j < 8; ++j) accO[i][j] = (f32x4){0.f,0.f,0.f,0.f};
  float mst[2][4], lst[2][4];
#pragma unroll
  for (int i = 0; i < 2; ++i)
#pragma unroll
    for (int j = 0; j < 4; ++j) { mst[i][j] = -1e30f; lst[i][j] = 0.f; }

  const int nt = qt*2 + 2;
  for (int t = 0; t < nt; ++t) {
    const int k0 = t*64;
    if (t) __syncthreads();
    // stage K row-major (coalesced)
#pragma unroll
    for (int c = 0; c < 4; ++c) {
      int g = c*256 + tid, key = g >> 4, ch = g & 15;
      uint4 kv = *(const uint4*)(Kp + (size_t)(k0 + key)*HD + ch*8);
      *(uint4*)&k_s[key*136 + ch*8] = kv;
    }
    // stage V transposed
#pragma unroll
    for (int c = 0; c < 4; ++c) {
      int g = c*256 + tid, key = g & 63, ch = (g >> 6) & 15;
      uint4 vv = *(const uint4*)(Vp + (size_t)(k0 + key)*HD + ch*8);
      unsigned short u[8];
      u[0]=vv.x&0xffff; u[1]=vv.x>>16; u[2]=vv.y&0xffff; u[3]=vv.y>>16;
      u[4]=vv.z&0xffff; u[5]=vv.z>>16; u[6]=vv.w&0xffff; u[7]=vv.w>>16;
#pragma unroll
      for (int j = 0; j < 8; ++j) v_t[(ch*8 + j)*72 + key] = u[j];
    }
    __syncthreads();

    // S = Q K^T  (per wave: 32 q x 64 key)
    f32x4 sA[2][4];
#pragma unroll
    for (int i = 0; i < 2; ++i)
#pragma unroll
      for (int j = 0; j < 4; ++j) sA[i][j] = (f32x4){0.f,0.f,0.f,0.f};
#pragma unroll
    for (int kf = 0; kf < 4; ++kf) {
      bf16x8 kfr[4];
#pragma unroll
      for (int ni = 0; ni < 4; ++ni)
        kfr[ni] = *(const bf16x8*)&k_s[(ni*16 + lx)*136 + kf*32 + lg*8];
#pragma unroll
      for (int mi = 0; mi < 2; ++mi)
#pragma unroll
        for (int ni = 0; ni < 4; ++ni)
          sA[mi][ni] = MFMA16(qf[mi][kf], kfr[ni], sA[mi][ni]);
    }

    // mask + online softmax + P -> LDS (bf16)
#pragma unroll
    for (int mi = 0; mi < 2; ++mi)
#pragma unroll
      for (int reg = 0; reg < 4; ++reg) {
        const int qabs = qw + mi*16 + lg*4 + reg;
        float sv0 = (k0 +  0 + lx <= qabs) ? sA[mi][0][reg] : -1e30f;
        float sv1 = (k0 + 16 + lx <= qabs) ? sA[mi][1][reg] : -1e30f;
        float sv2 = (k0 + 32 + lx <= qabs) ? sA[mi][2][reg] : -1e30f;
        float sv3 = (k0 + 48 + lx <= qabs) ? sA[mi][3][reg] : -1e30f;
        float pm = fmaxf(fmaxf(sv0, sv1), fmaxf(sv2, sv3));
        pm = fmaxf(pm, __shfl_xor(pm, 1));
        pm = fmaxf(pm, __shfl_xor(pm, 2));
        pm = fmaxf(pm, __shfl_xor(pm, 4));
        pm = fmaxf(pm, __shfl_xor(pm, 8));
        const float mo = mst[mi][reg];
        const float mn = fmaxf(mo, pm);
        const float fac = __expf(mo - mn);
        float p0 = __expf(sv0 - mn), p1 = __expf(sv1 - mn);
        float p2 = __expf(sv2 - mn), p3 = __expf(sv3 - mn);
        float rs = (p0 + p1) + (p2 + p3);
        rs += __shfl_xor(rs, 1); rs += __shfl_xor(rs, 2);
        rs += __shfl_xor(rs, 4); rs += __shfl_xor(rs, 8);
        mst[mi][reg] = mn;
        lst[mi][reg] = lst[mi][reg]*fac + rs;
#pragma unroll
        for (int nh = 0; nh < 8; ++nh) accO[mi][nh][reg] *= fac;
        unsigned short* pr = &p_s[w*32*72 + (mi*16 + lg*4 + reg)*72 + lx];
        pr[0]  = f2bf(p0);
        pr[16] = f2bf(p1);
        pr[32] = f2bf(p2);
        pr[48] = f2bf(p3);
      }

    // O += P V   (contraction over keys; V^T gives key-contiguous B frags)
#pragma unroll
    for (int ks = 0; ks < 2; ++ks) {
      bf16x8 pa[2];
#pragma unroll
      for (int mi = 0; mi < 2; ++mi)
        pa[mi] = *(const bf16x8*)&p_s[w*32*72 + (mi*16 + lx)*72 + ks*32 + lg*8];
#pragma unroll
      for (int nh = 0; nh < 8; ++nh) {
        bf16x8 vb = *(const bf16x8*)&v_t[(nh*16 + lx)*72 + ks*32 + lg*8];
#pragma unroll
        for (int mi = 0; mi < 2; ++mi)
          accO[mi][nh] = MFMA16(pa[mi], vb, accO[mi][nh]);
      }
    }
  }

  // normalize + store bf16 to (B,L,D) for the output GEMM
  unsigned short* aob = AO + ((size_t)b*LSEQ)*DM + (size_t)h*HD;
#pragma unroll
  for (int mi = 0; mi < 2; ++mi)
#pragma unroll
    for (int reg = 0; reg < 4; ++reg) {
      const float inv = 1.0f / lst[mi][reg];
      const int q = qw + mi*16 + lg*4 + reg;
      unsigned short* orow = aob + (size_t)q*DM;
#pragma unroll
      for (int nh = 0; nh < 8; ++nh)
        orow[nh*16 + lx] = f2bf(accO[mi][nh][reg] * inv);
    }
}

extern "C" void kernel_launch(void* const* d_in, const int* in_sizes, int n_in,
                              void* d_out, int out_size, void* d_ws, size_t ws_size,
                              hipStream_t stream)
{
  const float* x  = (const float*)d_in[0];
  const float* Wq = (const float*)d_in[1];
  const float* Wk = (const float*)d_in[2];
  const float* Wv = (const float*)d_in[3];
  const float* Wo = (const float*)d_in[4];
  float* out = (float*)d_out;

  // workspace carve (~81 MB)
  float* cosT = (float*)d_ws;                         // 2048*64
  float* sinT = cosT + LSEQ*64;
  unsigned short* xb  = (unsigned short*)(sinT + LSEQ*64);
  unsigned short* wqb = xb  + (size_t)MROWS*DM;       // 8.39M
  unsigned short* wkb = wqb + (size_t)DM*DM;          // 4.19M
  unsigned short* wvb = wkb + (size_t)KVD*DM;         // 1.05M
  unsigned short* wob = wvb + (size_t)KVD*DM;         // 1.05M
  unsigned short* qb  = wob + (size_t)DM*DM;          // 4.19M
  unsigned short* kb  = qb  + (size_t)BATCH*NH*LSEQ*HD;   // 8.39M
  unsigned short* vb  = kb  + (size_t)BATCH*NKV*LSEQ*HD;  // 2.10M
  unsigned short* aob = vb  + (size_t)BATCH*NKV*LSEQ*HD;  // 2.10M
                                                       // aob: 8.39M

  conv_k<<<2048, 256, 0, stream>>>(x,  xb,  MROWS*DM/4);
  conv_k<<<2048, 256, 0, stream>>>(Wq, wqb, DM*DM/4);
  conv_k<<<1024, 256, 0, stream>>>(Wk, wkb, KVD*DM/4);
  conv_k<<<1024, 256, 0, stream>>>(Wv, wvb, KVD*DM/4);
  conv_k<<<2048, 256, 0, stream>>>(Wo, wob, DM*DM/4);
  rope_tab_k<<<(LSEQ*64 + 255)/256, 256, 0, stream>>>(cosT, sinT);

  dim3 g1(MROWS/128, NQKV/128);   // 32 x 24
  gemm_k<0><<<g1, 256, 0, stream>>>(xb, wqb, wkb, wvb, qb, kb, vb, nullptr);

  rope_apply_k<<<(BATCH*(NH+NKV)*LSEQ*8)/256, 256, 0, stream>>>(qb, kb, cosT, sinT);

  dim3 g2(LSEQ/128, BATCH*NH);    // 16 x 32
  attn_k<<<g2, 256, 0, stream>>>(qb, kb, vb, aob);

  dim3 g3(MROWS/128, DM/128);     // 32 x 16
  gemm_k<1><<<g3, 256, 0, stream>>>(aob, wob, nullptr, nullptr, nullptr, nullptr, nullptr, out);
}